// Round 2
// baseline (711.404 us; speedup 1.0000x reference)
//
#include <hip/hip_runtime.h>
#include <hip/hip_bf16.h>
#include <math.h>

#define N_NODES 400000
#define DIM 256
#define NSEG 2048

typedef unsigned short u16;
typedef float floatx4 __attribute__((ext_vector_type(4)));
typedef __bf16 bf16x8 __attribute__((ext_vector_type(8)));
typedef _Float16 f16x8 __attribute__((ext_vector_type(8)));

__device__ __forceinline__ u16 f2bf(float f) {
    __hip_bfloat16 h = __float2bfloat16(f);
    return *reinterpret_cast<u16*>(&h);
}
__device__ __forceinline__ float sigf(float x) { return 1.0f / (1.0f + __expf(-x)); }

// butterfly sum across a 32-lane half-wave
__device__ __forceinline__ float reduce_half(float e) {
    e += __shfl_xor(e, 1);
    e += __shfl_xor(e, 2);
    e += __shfl_xor(e, 4);
    e += __shfl_xor(e, 8);
    e += __shfl_xor(e, 16);
    return e;
}

// ---------------- segment starts from sorted index (int32/int64 auto-detect) ----------------
__global__ void seg_starts_kernel(const int* __restrict__ idx32, int* __restrict__ seg) {
    int n = blockIdx.x * blockDim.x + threadIdx.x;
    if (n >= N_NODES) return;
    const bool is64 = (idx32[N_NODES - 1] == 0);
    int cur  = is64 ? idx32[2 * n] : idx32[n];
    int prev = (n == 0) ? -1 : (is64 ? idx32[2 * (n - 1)] : idx32[n - 1]);
    cur  = min(max(cur, -1), NSEG - 1);
    prev = min(max(prev, -1), NSEG - 1);
    for (int s = prev + 1; s <= cur; ++s) seg[s] = n;
    if (n == N_NODES - 1) {
        for (int s = cur + 1; s <= NSEG; ++s) seg[s] = N_NODES;
    }
}

// ---------------- weight prep: Wc = [Wih[:,0:256]+Whh | Wih[:,256:512]] (bf16), Wp -> bf16 ----
__global__ void prep_weights_kernel(const float* __restrict__ Wih, const float* __restrict__ Whh,
                                    const float* __restrict__ Wp,
                                    u16* __restrict__ Wc, u16* __restrict__ WpB) {
    int idx = blockIdx.x * blockDim.x + threadIdx.x;
    if (idx < 1024 * 512) {
        int j = idx >> 9, k = idx & 511;
        float v = Wih[(size_t)j * 512 + k];
        if (k < 256) v += Whh[(size_t)j * 256 + k];
        Wc[idx] = f2bf(v);
    }
    if (idx < 256 * 512) WpB[idx] = f2bf(Wp[idx]);
}

// ---------------- t=0 LSTM: all states zero -> gates = bih + bhh ----------------
__global__ void lstm_bias_kernel(const float* __restrict__ bih, const float* __restrict__ bhh,
                                 float* __restrict__ c, float* __restrict__ h,
                                 u16* __restrict__ A) {
    int idx = blockIdx.x * blockDim.x + threadIdx.x;
    if (idx >= NSEG * DIM) return;
    int b = idx >> 8, d = idx & 255;
    float gi = bih[d]       + bhh[d];
    float gg = bih[d + 512] + bhh[d + 512];
    float go = bih[d + 768] + bhh[d + 768];
    float cn = sigf(gi) * tanhf(gg);
    float hn = sigf(go) * tanhf(cn);
    c[idx] = cn;
    h[idx] = hn;
    A[(size_t)b * 512 + d] = f2bf(hn);
}

// ---------------- LSTM pointwise from fp32 gates ----------------
__global__ void lstm_pw_kernel(const float* __restrict__ gates,
                               const float* __restrict__ bih, const float* __restrict__ bhh,
                               float* __restrict__ c, float* __restrict__ h,
                               u16* __restrict__ A) {
    int idx = blockIdx.x * blockDim.x + threadIdx.x;
    if (idx >= NSEG * DIM) return;
    int b = idx >> 8, d = idx & 255;
    const float* g = gates + (size_t)b * 1024;
    float gi = g[d]       + bih[d]       + bhh[d];
    float gf = g[d + 256] + bih[d + 256] + bhh[d + 256];
    float gg = g[d + 512] + bih[d + 512] + bhh[d + 512];
    float go = g[d + 768] + bih[d + 768] + bhh[d + 768];
    float cn = sigf(gf) * c[idx] + sigf(gi) * tanhf(gg);
    float hn = sigf(go) * tanhf(cn);
    c[idx] = cn;
    h[idx] = hn;
    A[(size_t)b * 512 + d] = f2bf(hn);
}

// ---------------- t=0 attention (fp32 x) fused with x -> fp16 conversion ----------------
// 8 node-streams per block (half-wave owns a node, lane l32 owns dims 8*l32..8*l32+7);
// 2 nodes per stream per iteration + 2-node prefetch pair => 4-8 loads in flight per wave.
__global__ __launch_bounds__(256) void attn0_kernel(const float* __restrict__ x,
                                                    const int* __restrict__ seg,
                                                    const float* __restrict__ h,
                                                    u16* __restrict__ A,
                                                    _Float16* __restrict__ xh) {
    const int b = blockIdx.x;
    const int tid = threadIdx.x;
    const int wave = tid >> 6, lane = tid & 63;
    const int sub = lane >> 5, l32 = lane & 31;
    const int hs = wave * 2 + sub;          // stream id 0..7
    int s0 = seg[b], s1 = seg[b + 1];
    s0 = max(s0, 0);
    s1 = min(s1, N_NODES);

    if (s1 <= s0) {
        A[(size_t)b * 512 + 256 + tid] = (u16)0;
        return;
    }

    __shared__ float sm[8], sz[8];
    __shared__ float sr[8][256];

    float q[8];
    {
        const float4 q0 = *(const float4*)(h + (size_t)b * 256 + l32 * 8);
        const float4 q1 = *(const float4*)(h + (size_t)b * 256 + l32 * 8 + 4);
        q[0] = q0.x; q[1] = q0.y; q[2] = q0.z; q[3] = q0.w;
        q[4] = q1.x; q[5] = q1.y; q[6] = q1.z; q[7] = q1.w;
    }

    float m = -INFINITY, z = 0.f;
    float r[8] = {};

    int n = s0 + hs;
    bool v0 = n < s1, v1 = n + 8 < s1;
    float4 c0a = {}, c0b = {}, c1a = {}, c1b = {};
    if (v0) { c0a = *(const float4*)(x + (size_t)n * 256 + l32 * 8);
              c0b = *(const float4*)(x + (size_t)n * 256 + l32 * 8 + 4); }
    if (v1) { c1a = *(const float4*)(x + (size_t)(n + 8) * 256 + l32 * 8);
              c1b = *(const float4*)(x + (size_t)(n + 8) * 256 + l32 * 8 + 4); }

    while (v0) {
        const int nn = n + 16;
        const bool w0 = nn < s1, w1 = nn + 8 < s1;
        float4 n0a = {}, n0b = {}, n1a = {}, n1b = {};
        if (w0) { n0a = *(const float4*)(x + (size_t)nn * 256 + l32 * 8);
                  n0b = *(const float4*)(x + (size_t)nn * 256 + l32 * 8 + 4); }
        if (w1) { n1a = *(const float4*)(x + (size_t)(nn + 8) * 256 + l32 * 8);
                  n1b = *(const float4*)(x + (size_t)(nn + 8) * 256 + l32 * 8 + 4); }

        // fp16 cache store (each node stored exactly once across the grid)
        {
            f16x8 hv;
            hv[0] = (_Float16)c0a.x; hv[1] = (_Float16)c0a.y;
            hv[2] = (_Float16)c0a.z; hv[3] = (_Float16)c0a.w;
            hv[4] = (_Float16)c0b.x; hv[5] = (_Float16)c0b.y;
            hv[6] = (_Float16)c0b.z; hv[7] = (_Float16)c0b.w;
            *(f16x8*)(xh + (size_t)n * 256 + l32 * 8) = hv;
        }
        if (v1) {
            f16x8 hv;
            hv[0] = (_Float16)c1a.x; hv[1] = (_Float16)c1a.y;
            hv[2] = (_Float16)c1a.z; hv[3] = (_Float16)c1a.w;
            hv[4] = (_Float16)c1b.x; hv[5] = (_Float16)c1b.y;
            hv[6] = (_Float16)c1b.z; hv[7] = (_Float16)c1b.w;
            *(f16x8*)(xh + (size_t)(n + 8) * 256 + l32 * 8) = hv;
        }

        float e0 = c0a.x * q[0] + c0a.y * q[1] + c0a.z * q[2] + c0a.w * q[3]
                 + c0b.x * q[4] + c0b.y * q[5] + c0b.z * q[6] + c0b.w * q[7];
        float e1 = c1a.x * q[0] + c1a.y * q[1] + c1a.z * q[2] + c1a.w * q[3]
                 + c1b.x * q[4] + c1b.y * q[5] + c1b.z * q[6] + c1b.w * q[7];
        e0 = reduce_half(e0);
        e1 = reduce_half(e1);
        if (!v1) e1 = -INFINITY;

        float nm = fmaxf(m, fmaxf(e0, e1));
        float corr = __expf(m - nm);
        float p0 = __expf(e0 - nm);
        float p1 = __expf(e1 - nm);
        z = z * corr + p0 + p1;
        r[0] = r[0] * corr + p0 * c0a.x + p1 * c1a.x;
        r[1] = r[1] * corr + p0 * c0a.y + p1 * c1a.y;
        r[2] = r[2] * corr + p0 * c0a.z + p1 * c1a.z;
        r[3] = r[3] * corr + p0 * c0a.w + p1 * c1a.w;
        r[4] = r[4] * corr + p0 * c0b.x + p1 * c1b.x;
        r[5] = r[5] * corr + p0 * c0b.y + p1 * c1b.y;
        r[6] = r[6] * corr + p0 * c0b.z + p1 * c1b.z;
        r[7] = r[7] * corr + p0 * c0b.w + p1 * c1b.w;
        m = nm;

        c0a = n0a; c0b = n0b; c1a = n1a; c1b = n1b;
        v0 = w0; v1 = w1; n = nn;
    }

    if (l32 == 0) { sm[hs] = m; sz[hs] = z; }
    #pragma unroll
    for (int j = 0; j < 8; ++j) sr[hs][l32 * 8 + j] = r[j];
    __syncthreads();

    float M = sm[0];
    #pragma unroll
    for (int w = 1; w < 8; ++w) M = fmaxf(M, sm[w]);
    float zz = 0.f, rr = 0.f;
    #pragma unroll
    for (int w = 0; w < 8; ++w) {
        float cw = __expf(sm[w] - M);   // idle stream: exp(-inf)=0
        zz += cw * sz[w];
        rr += cw * sr[w][tid];
    }
    A[(size_t)b * 512 + 256 + tid] = f2bf(rr / zz);
}

// ---------------- t=1,2 attention on fp16 x: 2 nodes/stream/iter + prefetch pair ----------------
__global__ __launch_bounds__(256) void attn_h_kernel(const _Float16* __restrict__ xh,
                                                     const int* __restrict__ seg,
                                                     const float* __restrict__ h,
                                                     u16* __restrict__ A) {
    const int b = blockIdx.x;
    const int tid = threadIdx.x;
    const int wave = tid >> 6, lane = tid & 63;
    const int sub = lane >> 5, l32 = lane & 31;
    const int hs = wave * 2 + sub;

    int s0 = seg[b], s1 = seg[b + 1];
    s0 = max(s0, 0);
    s1 = min(s1, N_NODES);

    if (s1 <= s0) {
        A[(size_t)b * 512 + 256 + tid] = (u16)0;
        return;
    }

    __shared__ float sm[8], sz[8];
    __shared__ float sr[8][256];

    float q[8];
    {
        const float4 q0 = *(const float4*)(h + (size_t)b * 256 + l32 * 8);
        const float4 q1 = *(const float4*)(h + (size_t)b * 256 + l32 * 8 + 4);
        q[0] = q0.x; q[1] = q0.y; q[2] = q0.z; q[3] = q0.w;
        q[4] = q1.x; q[5] = q1.y; q[6] = q1.z; q[7] = q1.w;
    }

    float m = -INFINITY, z = 0.f;
    float r[8] = {};

    int n = s0 + hs;
    bool v0 = n < s1, v1 = n + 8 < s1;
    f16x8 c0 = {}, c1 = {};
    if (v0) c0 = *(const f16x8*)(xh + (size_t)n * 256 + l32 * 8);
    if (v1) c1 = *(const f16x8*)(xh + (size_t)(n + 8) * 256 + l32 * 8);

    while (v0) {
        const int nn = n + 16;
        const bool w0 = nn < s1, w1 = nn + 8 < s1;
        f16x8 p0v = {}, p1v = {};
        if (w0) p0v = *(const f16x8*)(xh + (size_t)nn * 256 + l32 * 8);
        if (w1) p1v = *(const f16x8*)(xh + (size_t)(nn + 8) * 256 + l32 * 8);

        float xf0[8], xf1[8];
        float e0 = 0.f, e1 = 0.f;
        #pragma unroll
        for (int j = 0; j < 8; ++j) { xf0[j] = (float)c0[j]; e0 += xf0[j] * q[j]; }
        #pragma unroll
        for (int j = 0; j < 8; ++j) { xf1[j] = (float)c1[j]; e1 += xf1[j] * q[j]; }
        e0 = reduce_half(e0);
        e1 = reduce_half(e1);
        if (!v1) e1 = -INFINITY;

        float nm = fmaxf(m, fmaxf(e0, e1));
        float corr = __expf(m - nm);
        float p0 = __expf(e0 - nm);
        float p1 = __expf(e1 - nm);
        z = z * corr + p0 + p1;
        #pragma unroll
        for (int j = 0; j < 8; ++j) r[j] = r[j] * corr + p0 * xf0[j] + p1 * xf1[j];
        m = nm;

        c0 = p0v; c1 = p1v;
        v0 = w0; v1 = w1; n = nn;
    }

    if (l32 == 0) { sm[hs] = m; sz[hs] = z; }
    #pragma unroll
    for (int j = 0; j < 8; ++j) sr[hs][l32 * 8 + j] = r[j];
    __syncthreads();

    float M = sm[0];
    #pragma unroll
    for (int w = 1; w < 8; ++w) M = fmaxf(M, sm[w]);
    float zz = 0.f, rr = 0.f;
    #pragma unroll
    for (int w = 0; w < 8; ++w) {
        float cw = __expf(sm[w] - M);
        zz += cw * sz[w];
        rr += cw * sr[w][tid];
    }
    A[(size_t)b * 512 + 256 + tid] = f2bf(rr / zz);
}

// ---------------- MFMA bf16 GEMM: C[M,N] = A[M,K] @ W[N,K]^T (+bias), fp32 out ----------
template<bool BIAS>
__global__ __launch_bounds__(256) void gemm_bt_kernel(const u16* __restrict__ Ag,
                                                      const u16* __restrict__ Wg,
                                                      const float* __restrict__ bias,
                                                      float* __restrict__ C,
                                                      int M, int N, int K) {
    __shared__ __align__(16) u16 As[64][40];
    __shared__ __align__(16) u16 Ws[64][40];

    const int tid = threadIdx.x;
    const int bm = blockIdx.x * 64;
    const int bn = blockIdx.y * 64;
    const int wave = tid >> 6, lane = tid & 63;
    const int wm = (wave & 1) * 32;
    const int wn = (wave >> 1) * 32;
    const int quad = lane >> 4;
    const int r16 = lane & 15;

    const int lrow = tid >> 2;
    const int lcol = (tid & 3) * 8;

    floatx4 acc[2][2] = {};

    for (int k0 = 0; k0 < K; k0 += 32) {
        *(uint4*)&As[lrow][lcol] = *(const uint4*)&Ag[(size_t)(bm + lrow) * K + k0 + lcol];
        *(uint4*)&Ws[lrow][lcol] = *(const uint4*)&Wg[(size_t)(bn + lrow) * K + k0 + lcol];
        __syncthreads();
        bf16x8 af0 = *(const bf16x8*)&As[wm + r16][quad * 8];
        bf16x8 af1 = *(const bf16x8*)&As[wm + 16 + r16][quad * 8];
        bf16x8 wf0 = *(const bf16x8*)&Ws[wn + r16][quad * 8];
        bf16x8 wf1 = *(const bf16x8*)&Ws[wn + 16 + r16][quad * 8];
        acc[0][0] = __builtin_amdgcn_mfma_f32_16x16x32_bf16(af0, wf0, acc[0][0], 0, 0, 0);
        acc[0][1] = __builtin_amdgcn_mfma_f32_16x16x32_bf16(af0, wf1, acc[0][1], 0, 0, 0);
        acc[1][0] = __builtin_amdgcn_mfma_f32_16x16x32_bf16(af1, wf0, acc[1][0], 0, 0, 0);
        acc[1][1] = __builtin_amdgcn_mfma_f32_16x16x32_bf16(af1, wf1, acc[1][1], 0, 0, 0);
        __syncthreads();
    }

    for (int tm = 0; tm < 2; ++tm)
        for (int tn = 0; tn < 2; ++tn)
            for (int j = 0; j < 4; ++j) {
                int row = bm + wm + tm * 16 + quad * 4 + j;
                int col = bn + wn + tn * 16 + r16;
                float v = acc[tm][tn][j];
                if (BIAS) v += bias[col];
                C[(size_t)row * N + col] = v;
            }
}

extern "C" void kernel_launch(void* const* d_in, const int* in_sizes, int n_in,
                              void* d_out, int out_size, void* d_ws, size_t ws_size,
                              hipStream_t stream) {
    const float* x   = (const float*)d_in[0];
    const int*   idx = (const int*)d_in[1];
    const float* Wih = (const float*)d_in[2];
    const float* Whh = (const float*)d_in[3];
    const float* bih = (const float*)d_in[4];
    const float* bhh = (const float*)d_in[5];
    const float* Wp  = (const float*)d_in[6];
    const float* bp  = (const float*)d_in[7];
    float* out = (float*)d_out;

    char* w = (char*)d_ws;
    int*   seg     = (int*)w;        w += 16384;
    u16*   A       = (u16*)w;        w += (size_t)NSEG * 512 * 2;       // 2 MB  [h | r] bf16
    u16*   Wc      = (u16*)w;        w += (size_t)1024 * 512 * 2;       // 1 MB
    u16*   WpB     = (u16*)w;        w += (size_t)256 * 512 * 2;        // 256 KB
    float* h_f32   = (float*)w;      w += (size_t)NSEG * DIM * 4;       // 2 MB
    float* c_f32   = (float*)w;      w += (size_t)NSEG * DIM * 4;       // 2 MB
    float* gates   = (float*)w;      w += (size_t)NSEG * 1024 * 4;      // 8 MB
    _Float16* xh   = (_Float16*)w;   w += (size_t)N_NODES * DIM * 2;    // 204.8 MB fp16 x cache

    seg_starts_kernel<<<(N_NODES + 255) / 256, 256, 0, stream>>>(idx, seg);
    prep_weights_kernel<<<(1024 * 512 + 255) / 256, 256, 0, stream>>>(Wih, Whh, Wp, Wc, WpB);

    // t = 0: states are zero -> bias-only LSTM; attention also emits the fp16 x cache
    lstm_bias_kernel<<<(NSEG * DIM + 255) / 256, 256, 0, stream>>>(bih, bhh, c_f32, h_f32, A);
    attn0_kernel<<<NSEG, 256, 0, stream>>>(x, seg, h_f32, A, xh);

    // t = 1, 2: attention reads the fp16 cache (L3-resident: 204.8 MB < 256 MB)
    for (int t = 1; t < 3; ++t) {
        gemm_bt_kernel<false><<<dim3(2048 / 64, 1024 / 64), 256, 0, stream>>>(
            A, Wc, nullptr, gates, 2048, 1024, 512);
        lstm_pw_kernel<<<(NSEG * DIM + 255) / 256, 256, 0, stream>>>(gates, bih, bhh,
                                                                     c_f32, h_f32, A);
        attn_h_kernel<<<NSEG, 256, 0, stream>>>(xh, seg, h_f32, A);
    }

    // out = q_star @ Wp^T + bp
    gemm_bt_kernel<true><<<dim3(2048 / 64, 256 / 64), 256, 0, stream>>>(
        A, WpB, bp, out, 2048, 256, 512);
}